// Round 1
// baseline (196.495 us; speedup 1.0000x reference)
//
#include <hip/hip_runtime.h>

// PdfSampler: B rays, 128 weights -> 128 samples.
// Outputs concatenated: pts [B,128,3], z [B,128], s [B,128] (z == s).
// One wave (64 lanes) per ray; 4 rays per 256-thread block.

#define NBINS 128
#define NSAMP 128

__global__ __launch_bounds__(256) void pdf_sampler_kernel(
    const float* __restrict__ rays_o,
    const float* __restrict__ rays_d,
    const float* __restrict__ weights,
    float* __restrict__ out,
    int B)
{
    __shared__ float cdf_lds[4][132];   // 129 used, padded
    __shared__ float s_lds[4 * 128];    // per-ray samples, ray-major
    __shared__ float od_lds[4][6];      // o0 o1 o2 d0 d1 d2 per ray

    const int tid  = threadIdx.x;
    const int wave = tid >> 6;
    const int lane = tid & 63;
    const int r0   = blockIdx.x * 4;
    const int r    = r0 + wave;

    // stage rays_o/rays_d for the block's 4 rays
    if (tid < 12) {
        int ray = tid / 3, c = tid - ray * 3;
        od_lds[ray][c] = rays_o[(r0 + ray) * 3 + c];
    } else if (tid < 24) {
        int t2 = tid - 12;
        int ray = t2 / 3, c = t2 - ray * 3;
        od_lds[ray][3 + c] = rays_d[(r0 + ray) * 3 + c];
    }

    // ---- load 2 weights/lane, coalesced float2 ----
    const float2 wv = reinterpret_cast<const float2*>(weights + (size_t)r * 128)[lane];
    const float w0 = wv.x + 1e-6f;
    const float w1 = wv.y + 1e-6f;
    const float ps = w0 + w1;

    // inclusive wave scan of pair sums
    float sc = ps;
    #pragma unroll
    for (int off = 1; off < 64; off <<= 1) {
        float n = __shfl_up(sc, off, 64);
        if (lane >= off) sc += n;
    }
    const float total = __shfl(sc, 63, 64);
    const float rtot  = 1.0f / total;

    float* cdf = cdf_lds[wave];
    if (lane == 0) cdf[0] = 0.0f;
    cdf[2 * lane + 1] = (sc - w1) * rtot;
    cdf[2 * lane + 2] = sc * rtot;
    __syncthreads();

    // ---- 2 samples per lane: branchless searchsorted(right) + lerp ----
    const float DELTA = 49.0f / 127.0f;
    #pragma unroll
    for (int q = 0; q < 2; ++q) {
        const int j = 2 * lane + q;
        const float u = (float)j / 127.0f;

        // pos = max{k in [0,127] : cdf[k] <= u}; cdf[0]=0 so pos>=0.
        int pos = 0;
        #pragma unroll
        for (int b = 64; b >= 1; b >>= 1) {
            pos += (cdf[pos + b] <= u) ? b : 0;   // pos+b <= 127 always
        }
        const int above = pos + 1;                 // in [1,128]
        const int below = pos;

        const float clo = cdf[below];
        const float chi = cdf[above];
        float blo = 1.0f + ((float)below - 0.5f) * DELTA;
        if (below == 0) blo = 1.0f;
        float bhi = 1.0f + ((float)above - 0.5f) * DELTA;
        if (above == 128) bhi = 50.0f;

        float denom = chi - clo;
        if (denom < 1e-6f) denom = 1.0f;
        const float t = (u - clo) / denom;
        // s already non-decreasing up to ~1e-6 -> sort skipped
        s_lds[wave * 128 + j] = blo + t * (bhi - blo + 1e-6f);
    }
    __syncthreads();

    // ---- coalesced float4 output stage ----
    // pts: 4 rays * 384 floats = 384 float4 chunks
    float4* outPts = reinterpret_cast<float4*>(out + (size_t)r0 * 384);
    for (int c = tid; c < 384; c += 256) {
        const int m0   = 4 * c;
        const int rayl = m0 / 384;
        const int rem  = m0 - rayl * 384;
        float4 v;
        float* vp = &v.x;
        #pragma unroll
        for (int k = 0; k < 4; ++k) {
            const int rr     = rem + k;
            const int sample = rr / 3;
            const int comp   = rr - sample * 3;
            vp[k] = od_lds[rayl][comp] + od_lds[rayl][3 + comp] * s_lds[rayl * 128 + sample];
        }
        outPts[c] = v;
    }

    // z and s regions: each 512 contiguous floats for this block = 128 float4
    const size_t zBase = (size_t)B * 384 + (size_t)r0 * 128;
    const size_t sBase = (size_t)B * 512 + (size_t)r0 * 128;
    if (tid < 128) {
        float4 v = reinterpret_cast<const float4*>(s_lds)[tid];
        reinterpret_cast<float4*>(out + zBase)[tid] = v;
    } else {
        const int t2 = tid - 128;
        float4 v = reinterpret_cast<const float4*>(s_lds)[t2];
        reinterpret_cast<float4*>(out + sBase)[t2] = v;
    }
}

extern "C" void kernel_launch(void* const* d_in, const int* in_sizes, int n_in,
                              void* d_out, int out_size, void* d_ws, size_t ws_size,
                              hipStream_t stream) {
    const float* rays_o  = (const float*)d_in[0];
    const float* rays_d  = (const float*)d_in[1];
    const float* weights = (const float*)d_in[2];
    float* out = (float*)d_out;

    const int B = in_sizes[0] / 3;      // 262144; divisible by 4
    const int blocks = B / 4;
    pdf_sampler_kernel<<<blocks, 256, 0, stream>>>(rays_o, rays_d, weights, out, B);
}

// Round 2
// 127.313 us; speedup vs baseline: 1.5434x; 1.5434x over previous
//
#include <hip/hip_runtime.h>

// PdfSampler: B rays, 128 weights -> 128 samples.
// Outputs concatenated: pts [B,128,3], z [B,128], s [B,128] (z == s).
// 2 rays per wave (ILP), 8 rays per 256-thread block, NT stores.

typedef float __attribute__((ext_vector_type(2))) f32x2;
typedef float __attribute__((ext_vector_type(4))) f32x4;

__device__ __forceinline__ float lerp_sample(const float* __restrict__ cdf, int pos, float u) {
    const float DELTA = 49.0f / 127.0f;
    const int above = pos + 1;
    const float clo = cdf[pos];
    const float chi = cdf[above];
    float blo = (pos == 0)    ? 1.0f  : 1.0f + ((float)pos - 0.5f) * DELTA;
    float bhi = (above == 128) ? 50.0f : 1.0f + ((float)above - 0.5f) * DELTA;
    float denom = chi - clo;
    if (denom < 1e-6f) denom = 1.0f;
    const float t = (u - clo) / denom;
    return blo + t * (bhi - blo + 1e-6f);
}

__global__ __launch_bounds__(256) void pdf_sampler_kernel(
    const float* __restrict__ rays_o,
    const float* __restrict__ rays_d,
    const float* __restrict__ weights,
    float* __restrict__ out,
    int B)
{
    __shared__ float cdf_lds[8][132];   // 129 used, padded
    __shared__ float s_lds[8 * 128];    // per-ray samples, ray-major
    __shared__ float od_lds[8][6];      // o0 o1 o2 d0 d1 d2 per ray

    const int tid  = threadIdx.x;
    const int wave = tid >> 6;
    const int lane = tid & 63;
    const int r0   = blockIdx.x * 8;
    const int rayA = 2 * wave;          // local rays handled by this wave
    const int rayB = rayA + 1;
    const size_t gA = (size_t)(r0 + rayA);
    const size_t gB = (size_t)(r0 + rayB);

    // stage rays_o/rays_d for the block's 8 rays
    if (tid < 24) {
        int ray = tid / 3, c = tid - ray * 3;
        od_lds[ray][c] = rays_o[(r0 + ray) * 3 + c];
    } else if (tid < 48) {
        int t2 = tid - 24;
        int ray = t2 / 3, c = t2 - ray * 3;
        od_lds[ray][3 + c] = rays_d[(r0 + ray) * 3 + c];
    }

    // ---- 2 independent weight loads (coalesced float2, 1 KB back-to-back) ----
    const float2 wa = reinterpret_cast<const float2*>(weights)[gA * 64 + lane];
    const float2 wb = reinterpret_cast<const float2*>(weights)[gB * 64 + lane];
    const float a1 = wa.x + 1e-6f, a2 = wa.y + 1e-6f;
    const float b1 = wb.x + 1e-6f, b2 = wb.y + 1e-6f;

    // two interleaved inclusive wave scans of pair sums (independent chains)
    float sa = a1 + a2, sb = b1 + b2;
    #pragma unroll
    for (int off = 1; off < 64; off <<= 1) {
        float na = __shfl_up(sa, off, 64);
        float nb = __shfl_up(sb, off, 64);
        if (lane >= off) { sa += na; sb += nb; }
    }
    const float inva = 1.0f / __shfl(sa, 63, 64);
    const float invb = 1.0f / __shfl(sb, 63, 64);

    float* cdfA = cdf_lds[rayA];
    float* cdfB = cdf_lds[rayB];
    if (lane == 0) { cdfA[0] = 0.0f; cdfB[0] = 0.0f; }
    cdfA[2 * lane + 1] = (sa - a2) * inva;
    cdfA[2 * lane + 2] = sa * inva;
    cdfB[2 * lane + 1] = (sb - b2) * invb;
    cdfB[2 * lane + 2] = sb * invb;
    __syncthreads();

    // ---- 4 samples (2 per ray), interleaved branchless searchsorted(right) ----
    float svA[2], svB[2];
    #pragma unroll
    for (int q = 0; q < 2; ++q) {
        const int j = 2 * lane + q;
        const float u = (float)j * (1.0f / 127.0f);
        int pa = 0, pb = 0;
        #pragma unroll
        for (int b = 64; b >= 1; b >>= 1) {
            pa += (cdfA[pa + b] <= u) ? b : 0;   // pa+b <= 127 always
            pb += (cdfB[pb + b] <= u) ? b : 0;
        }
        // s already non-decreasing up to ~1e-6 -> sort skipped
        svA[q] = lerp_sample(cdfA, pa, u);
        svB[q] = lerp_sample(cdfB, pb, u);
        s_lds[rayA * 128 + j] = svA[q];
        s_lds[rayB * 128 + j] = svB[q];
    }

    // ---- z and s stores straight from registers (coalesced float2, NT) ----
    {
        const size_t zBase = (size_t)B * 384;
        const size_t sBase = (size_t)B * 512;
        f32x2 vA; vA[0] = svA[0]; vA[1] = svA[1];
        f32x2 vB; vB[0] = svB[0]; vB[1] = svB[1];
        f32x2* zA = reinterpret_cast<f32x2*>(out + zBase + gA * 128);
        f32x2* zB = reinterpret_cast<f32x2*>(out + zBase + gB * 128);
        f32x2* sA = reinterpret_cast<f32x2*>(out + sBase + gA * 128);
        f32x2* sB = reinterpret_cast<f32x2*>(out + sBase + gB * 128);
        __builtin_nontemporal_store(vA, zA + lane);
        __builtin_nontemporal_store(vB, zB + lane);
        __builtin_nontemporal_store(vA, sA + lane);
        __builtin_nontemporal_store(vB, sB + lane);
    }
    __syncthreads();

    // ---- pts: 8 rays * 384 floats = 768 float4 chunks, coalesced NT ----
    f32x4* outPts = reinterpret_cast<f32x4*>(out + (size_t)r0 * 384);
    #pragma unroll
    for (int it = 0; it < 3; ++it) {
        const int c    = tid + it * 256;       // 0..767
        const int m0   = 4 * c;
        const int rayl = m0 / 384;
        const int rem  = m0 - rayl * 384;
        f32x4 v;
        #pragma unroll
        for (int k = 0; k < 4; ++k) {
            const int rr     = rem + k;
            const int sample = rr / 3;
            const int comp   = rr - sample * 3;
            v[k] = od_lds[rayl][comp] + od_lds[rayl][3 + comp] * s_lds[rayl * 128 + sample];
        }
        __builtin_nontemporal_store(v, outPts + c);
    }
}

extern "C" void kernel_launch(void* const* d_in, const int* in_sizes, int n_in,
                              void* d_out, int out_size, void* d_ws, size_t ws_size,
                              hipStream_t stream) {
    const float* rays_o  = (const float*)d_in[0];
    const float* rays_d  = (const float*)d_in[1];
    const float* weights = (const float*)d_in[2];
    float* out = (float*)d_out;

    const int B = in_sizes[0] / 3;      // 262144; divisible by 8
    const int blocks = B / 8;
    pdf_sampler_kernel<<<blocks, 256, 0, stream>>>(rays_o, rays_d, weights, out, B);
}